// Round 1
// baseline (1524.067 us; speedup 1.0000x reference)
//
#include <hip/hip_runtime.h>
#include <cstddef>

#define NPTS 32768
#define DDIM 128
#define KCB  1024

// ---------- numeric helpers ----------

// exp(x) for |x| <= ~290, rel err ~5e-9 (degree-7 Taylor + Cody-Waite)
__device__ __forceinline__ double fast_exp_d(double x) {
  const double LOG2E  = 1.4426950408889634074;
  const double LN2_HI = 6.93147180369123816490e-01;
  const double LN2_LO = 1.90821492927058770002e-10;
  double kd = rint(x * LOG2E);
  double r  = fma(-kd, LN2_HI, x);
  r = fma(-kd, LN2_LO, r);
  double p = 1.0 / 5040.0;
  p = fma(p, r, 1.0 / 720.0);
  p = fma(p, r, 1.0 / 120.0);
  p = fma(p, r, 1.0 / 24.0);
  p = fma(p, r, 1.0 / 6.0);
  p = fma(p, r, 0.5);
  p = fma(p, r, 1.0);
  p = fma(p, r, 1.0);
  long long ib = ((long long)((int)kd + 1023)) << 52;
  return p * __longlong_as_double(ib);
}

// -(dc)/epsilon in f64, with dc computed in f32 exactly like the reference
__device__ __forceinline__ double score_exponent(float cv, float middle, float amplitude) {
  float d  = (1.0f - cv) / 0.2f;
  float dc = (d - middle) / amplitude;
  return (double)dc * (-(1.0 / 0.005));
}

// order-preserving f32 <-> u32 encode for atomic min/max
__device__ __forceinline__ unsigned enc_f32(float f) {
  unsigned u = __float_as_uint(f);
  return (u & 0x80000000u) ? ~u : (u | 0x80000000u);
}
__device__ __forceinline__ float dec_f32(unsigned e) {
  unsigned u = (e & 0x80000000u) ? (e & 0x7FFFFFFFu) : ~e;
  return __uint_as_float(u);
}

// ---------- kernels ----------

__global__ __launch_bounds__(1024) void vq_init_kernel(double* __restrict__ u123,
                                                       double* __restrict__ loss_acc,
                                                       unsigned* __restrict__ maxenc,
                                                       unsigned* __restrict__ minenc) {
  int t = threadIdx.x;
  for (int i = t; i < 3 * KCB; i += 1024) u123[i] = 0.0;
  if (t == 0) {
    loss_acc[0] = 0.0;
    *maxenc = 0u;
    *minenc = 0xFFFFFFFFu;
  }
}

__global__ __launch_bounds__(128) void vq_normalize_rows(const float* __restrict__ in,
                                                         float* __restrict__ out) {
  int row = blockIdx.x;
  int t = threadIdx.x;
  float v = in[(size_t)row * DDIM + t];
  float s = v * v;
#pragma unroll
  for (int off = 32; off; off >>= 1) s += __shfl_down(s, off, 64);
  __shared__ float red[2];
  if ((t & 63) == 0) red[t >> 6] = s;
  __syncthreads();
  float norm = sqrtf(red[0] + red[1]);
  out[(size_t)row * DDIM + t] = v / fmaxf(norm, 1e-12f);
}

#define BM 128
#define BN 128
#define BK 32

__global__ __launch_bounds__(256) void vq_gemm_cos(const float* __restrict__ A,
                                                   const float* __restrict__ B,
                                                   float* __restrict__ Cm,
                                                   unsigned* __restrict__ maxenc,
                                                   unsigned* __restrict__ minenc) {
  __shared__ float As[BM][BK + 4];
  __shared__ float Bs[BN][BK + 4];
  int tid = threadIdx.x;
  int tx = tid & 15;   // column group
  int ty = tid >> 4;   // row group
  int n0 = blockIdx.y * BM;
  int c0 = blockIdx.x * BN;
  float acc[8][8];
#pragma unroll
  for (int i = 0; i < 8; ++i)
#pragma unroll
    for (int j = 0; j < 8; ++j) acc[i][j] = 0.0f;

  for (int kc = 0; kc < DDIM; kc += BK) {
#pragma unroll
    for (int l = 0; l < 4; ++l) {
      int idx = tid + l * 256;     // 0..1023 float4 groups
      int row = idx >> 3;          // 0..127
      int k4  = (idx & 7) * 4;     // 0..28
      *(float4*)&As[row][k4] = *(const float4*)&A[(size_t)(n0 + row) * DDIM + kc + k4];
      *(float4*)&Bs[row][k4] = *(const float4*)&B[(size_t)(c0 + row) * DDIM + kc + k4];
    }
    __syncthreads();
#pragma unroll
    for (int kk = 0; kk < BK; kk += 4) {
      float4 av[8], bv[8];
#pragma unroll
      for (int i = 0; i < 8; ++i) av[i] = *(const float4*)&As[ty + 16 * i][kk];
#pragma unroll
      for (int j = 0; j < 8; ++j) bv[j] = *(const float4*)&Bs[tx + 16 * j][kk];
#pragma unroll
      for (int i = 0; i < 8; ++i)
#pragma unroll
        for (int j = 0; j < 8; ++j)
          acc[i][j] += av[i].x * bv[j].x + av[i].y * bv[j].y +
                       av[i].z * bv[j].z + av[i].w * bv[j].w;
    }
    __syncthreads();
  }

  float mx = -3.402823466e38f, mn = 3.402823466e38f;
#pragma unroll
  for (int i = 0; i < 8; ++i) {
#pragma unroll
    for (int j = 0; j < 8; ++j) {
      float v = acc[i][j];
      mx = fmaxf(mx, v);
      mn = fminf(mn, v);
      Cm[(size_t)(n0 + ty + 16 * i) * KCB + (c0 + tx + 16 * j)] = v;
    }
  }
#pragma unroll
  for (int off = 32; off; off >>= 1) {
    mx = fmaxf(mx, __shfl_down(mx, off, 64));
    mn = fminf(mn, __shfl_down(mn, off, 64));
  }
  if ((tid & 63) == 0) {
    atomicMax(maxenc, enc_f32(mx));
    atomicMin(minenc, enc_f32(mn));
  }
}

__global__ void vq_scalarize(const unsigned* __restrict__ maxenc,
                             const unsigned* __restrict__ minenc,
                             float* __restrict__ scal) {
  float cosmax = dec_f32(*maxenc);
  float cosmin = dec_f32(*minenc);
  // d = (1-cos)/0.2 is monotone decreasing in cos; f32 rounding is monotone,
  // so d.max() == f32((1-cosmin)/0.2), d.min() == f32((1-cosmax)/0.2)
  float mx_d = (1.0f - cosmin) / 0.2f;
  float mn_d = (1.0f - cosmax) / 0.2f;
  float middle = (mx_d + mn_d) / 2.0f;
  float amplitude = fmaxf(mx_d - middle + 1e-5f, 1e-5f);
  scal[0] = middle;
  scal[1] = amplitude;
}

#define UROWS 128
// u[k] += sum_n E[n,k] * (Cvec ? Cvec[n] : 1)
__global__ __launch_bounds__(256) void vq_u_pass(const float* __restrict__ Cm,
                                                 const float* __restrict__ scal,
                                                 const double* __restrict__ Cvec,
                                                 double* __restrict__ u) {
  int k = blockIdx.x * 256 + threadIdx.x;
  int n0 = blockIdx.y * UROWS;
  float middle = scal[0], amplitude = scal[1];
  double s = 0.0;
  for (int r = 0; r < UROWS; ++r) {
    int n = n0 + r;
    float cv = Cm[(size_t)n * KCB + k];
    double e = fast_exp_d(score_exponent(cv, middle, amplitude));
    double w = Cvec ? Cvec[n] : 1.0;
    s += e * w;
  }
  atomicAdd(&u[k], s);
}

// mode 0: also compute alpha = 1/max(sum u, 1e-5); mode 2: also lnR
__global__ __launch_bounds__(1024) void vq_finalize_u(const double* __restrict__ u,
                                                      double* __restrict__ alpha_p,
                                                      double* __restrict__ R,
                                                      double* __restrict__ lnR,
                                                      int mode) {
  int k = threadIdx.x;
  double uk = u[k];
  __shared__ double red[16];
  __shared__ double s_alpha;
  if (mode == 0) {
    double s = uk;
#pragma unroll
    for (int off = 32; off; off >>= 1) s += __shfl_down(s, off, 64);
    if ((k & 63) == 0) red[k >> 6] = s;
    __syncthreads();
    if (k == 0) {
      double s0 = 0.0;
      for (int w = 0; w < 16; ++w) s0 += red[w];
      double a = 1.0 / fmax(s0, 1e-5);
      s_alpha = a;
      alpha_p[0] = a;
    }
    __syncthreads();
  }
  double alpha = (mode == 0) ? s_alpha : alpha_p[0];
  double r = 1.0 / (alpha * 1024.0 * uk);
  R[k] = r;
  if (mode == 2) lnR[k] = log(r);
}

// C[n] = 1/(alpha * N * sum_k E[n,k]*R[k])
__global__ __launch_bounds__(256) void vq_v_pass(const float* __restrict__ Cm,
                                                 const float* __restrict__ scal,
                                                 const double* __restrict__ R,
                                                 const double* __restrict__ alpha_p,
                                                 double* __restrict__ Cvec) {
  int n = blockIdx.x;
  int t = threadIdx.x;
  float middle = scal[0], amplitude = scal[1];
  double s = 0.0;
#pragma unroll
  for (int j = 0; j < 4; ++j) {
    int k = t + 256 * j;
    float cv = Cm[(size_t)n * KCB + k];
    s += fast_exp_d(score_exponent(cv, middle, amplitude)) * R[k];
  }
#pragma unroll
  for (int off = 32; off; off >>= 1) s += __shfl_down(s, off, 64);
  __shared__ double red[4];
  if ((t & 63) == 0) red[t >> 6] = s;
  __syncthreads();
  if (t == 0) {
    double v = red[0] + red[1] + red[2] + red[3];
    Cvec[n] = 1.0 / (alpha_p[0] * 32768.0 * v);
  }
}

// per row: argmax_k(-dc/eps + lnR[k]) -> index, gather codebook, CE loss
__global__ __launch_bounds__(256) void vq_final_pass(const float* __restrict__ Cm,
                                                     const float* __restrict__ x,
                                                     const float* __restrict__ cb,
                                                     const double* __restrict__ lnR,
                                                     const float* __restrict__ scal,
                                                     double* __restrict__ loss_acc,
                                                     float* __restrict__ out_xq,
                                                     float* __restrict__ out_idx) {
  int n = blockIdx.x;
  int t = threadIdx.x;
  float middle = scal[0], amplitude = scal[1];
  __shared__ double sred[4];
  __shared__ int skred[4];
  __shared__ float sfred[4];
  __shared__ int s_bk;
  __shared__ float s_lbest;

  float lv[4];
  double best = -1.0e308;
  int bestk = 0;
  float lmax = -3.402823466e38f;
#pragma unroll
  for (int j = 0; j < 4; ++j) {
    int k = t + 256 * j;
    float cv = Cm[(size_t)n * KCB + k];
    double score = score_exponent(cv, middle, amplitude) + lnR[k];
    if (score > best) { best = score; bestk = k; }  // ascending k: strict > keeps first max
    float l = cv / 0.2f;
    lv[j] = l;
    lmax = fmaxf(lmax, l);
  }
#pragma unroll
  for (int off = 32; off; off >>= 1) {
    double ob = __shfl_down(best, off, 64);
    int ok = __shfl_down(bestk, off, 64);
    float om = __shfl_down(lmax, off, 64);
    if (ob > best || (ob == best && ok < bestk)) { best = ob; bestk = ok; }
    lmax = fmaxf(lmax, om);
  }
  int lane = t & 63, wid = t >> 6;
  if (lane == 0) { sred[wid] = best; skred[wid] = bestk; sfred[wid] = lmax; }
  __syncthreads();
  if (t == 0) {
    double b = sred[0]; int bk = skred[0]; float m = sfred[0];
    for (int w = 1; w < 4; ++w) {
      if (sred[w] > b || (sred[w] == b && skred[w] < bk)) { b = sred[w]; bk = skred[w]; }
      m = fmaxf(m, sfred[w]);
    }
    s_bk = bk;
    sfred[0] = m;
  }
  __syncthreads();
  int bk = s_bk;
  float lm = sfred[0];
  double se = 0.0;
#pragma unroll
  for (int j = 0; j < 4; ++j) {
    se += (double)expf(lv[j] - lm);
    if (t + 256 * j == bk) s_lbest = lv[j];
  }
#pragma unroll
  for (int off = 32; off; off >>= 1) se += __shfl_down(se, off, 64);
  __syncthreads();  // protect sred reuse; also orders s_lbest write before read
  if (lane == 0) sred[wid] = se;
  __syncthreads();
  if (t == 0) {
    double set = sred[0] + sred[1] + sred[2] + sred[3];
    double loss_n = -((double)s_lbest - (double)lm - log(set));
    atomicAdd(loss_acc, loss_n);
    out_idx[n] = (float)bk;
  }
  if (t < DDIM) {
    float xf = x[(size_t)n * DDIM + t];
    float cbv = cb[(size_t)bk * DDIM + t];
    out_xq[(size_t)n * DDIM + t] = xf + (cbv - xf);  // STE forward, f32 like ref
  }
}

__global__ void vq_loss_div(const double* __restrict__ loss_acc, float* __restrict__ out_loss) {
  out_loss[0] = (float)(loss_acc[0] / 32768.0);
}

// ---------- launch ----------

extern "C" void kernel_launch(void* const* d_in, const int* in_sizes, int n_in,
                              void* d_out, int out_size, void* d_ws, size_t ws_size,
                              hipStream_t stream) {
  const float* x  = (const float*)d_in[0];
  const float* cb = (const float*)d_in[1];
  float* out = (float*)d_out;
  float* out_xq   = out;
  float* out_loss = out + (size_t)NPTS * DDIM;
  float* out_idx  = out + (size_t)NPTS * DDIM + 1;

  // workspace layout (~152 MB)
  char* w = (char*)d_ws;
  float* xn   = (float*)w;                         // N*D
  float* cn   = xn + (size_t)NPTS * DDIM;          // K*D
  float* cosm = cn + (size_t)KCB * DDIM;           // N*K
  double* u1  = (double*)(cosm + (size_t)NPTS * KCB);
  double* u2  = u1 + KCB;
  double* u3  = u2 + KCB;
  double* R   = u3 + KCB;
  double* lnR = R + KCB;
  double* Cv  = lnR + KCB;                         // N
  double* alpha_p  = Cv + NPTS;
  double* loss_acc = alpha_p + 1;
  unsigned* maxenc = (unsigned*)(loss_acc + 1);
  unsigned* minenc = maxenc + 1;
  float* scal = (float*)(minenc + 1);              // middle, amplitude

  vq_init_kernel<<<1, 1024, 0, stream>>>(u1, loss_acc, maxenc, minenc);
  vq_normalize_rows<<<NPTS, 128, 0, stream>>>(x, xn);
  vq_normalize_rows<<<KCB, 128, 0, stream>>>(cb, cn);
  vq_gemm_cos<<<dim3(KCB / BN, NPTS / BM), 256, 0, stream>>>(xn, cn, cosm, maxenc, minenc);
  vq_scalarize<<<1, 1, 0, stream>>>(maxenc, minenc, scal);

  dim3 ugrid(KCB / 256, NPTS / UROWS);
  vq_u_pass<<<ugrid, 256, 0, stream>>>(cosm, scal, nullptr, u1);
  vq_finalize_u<<<1, 1024, 0, stream>>>(u1, alpha_p, R, lnR, 0);
  vq_v_pass<<<NPTS, 256, 0, stream>>>(cosm, scal, R, alpha_p, Cv);
  vq_u_pass<<<ugrid, 256, 0, stream>>>(cosm, scal, Cv, u2);
  vq_finalize_u<<<1, 1024, 0, stream>>>(u2, alpha_p, R, lnR, 1);
  vq_v_pass<<<NPTS, 256, 0, stream>>>(cosm, scal, R, alpha_p, Cv);
  vq_u_pass<<<ugrid, 256, 0, stream>>>(cosm, scal, Cv, u3);
  vq_finalize_u<<<1, 1024, 0, stream>>>(u3, alpha_p, R, lnR, 2);

  vq_final_pass<<<NPTS, 256, 0, stream>>>(cosm, x, cb, lnR, scal, loss_acc, out_xq, out_idx);
  vq_loss_div<<<1, 1, 0, stream>>>(loss_acc, out_loss);
}

// Round 2
// 552.261 us; speedup vs baseline: 2.7597x; 2.7597x over previous
//
#include <hip/hip_runtime.h>
#include <cstddef>

#define NPTS 32768
#define DDIM 128
#define KCB  1024

// ---------- numeric helpers ----------

__device__ __forceinline__ float hw_exp2(float x) {
#if __has_builtin(__builtin_amdgcn_exp2f)
  return __builtin_amdgcn_exp2f(x);
#else
  return exp2f(x);
#endif
}

__device__ __forceinline__ void atomic_add_f64(double* p, double v) {
  __hip_atomic_fetch_add(p, v, __ATOMIC_RELAXED, __HIP_MEMORY_SCOPE_AGENT);
}

// correctly-rounded f32 division via 2-FMA Markstein refinement (rc = RN(1/c))
__device__ __forceinline__ float div_mark(float x, float c, float rc) {
  float q0 = x * rc;
  float r  = fmaf(-c, q0, x);
  return fmaf(r, rc, q0);
}

// E = exp(-dc/eps) with f64 range, rel err ~8e-8 (errors average out in the
// Sinkhorn row/col sums; NOT used for the final argmax score).
// xl2 = dc * (-200*log2(e)); E = 2^xl2
__device__ __forceinline__ double sweep_E(float cv, float middle, float amp, float rc_amp) {
  float d  = div_mark(1.0f - cv, 0.2f, 1.0f / 0.2f);
  float dc = div_mark(d - middle, amp, rc_amp);
  double xl2 = (double)dc * (-288.53900817779268);  // 200*log2(e)
  double kd  = rint(xl2);
  float  fr  = (float)(xl2 - kd);
  float  m   = hw_exp2(fr);
  long long bits = ((long long)(1023 + (int)kd)) << 52;
  return (double)m * __longlong_as_double(bits);
}

// bit-exact path (matches jnp f32 ops) for the final argmax score exponent
__device__ __forceinline__ double score_exponent(float cv, float middle, float amplitude) {
  float d  = (1.0f - cv) / 0.2f;
  float dc = (d - middle) / amplitude;
  return (double)dc * (-(1.0 / 0.005));
}

// order-preserving f32 <-> u32 encode for atomic min/max
__device__ __forceinline__ unsigned enc_f32(float f) {
  unsigned u = __float_as_uint(f);
  return (u & 0x80000000u) ? ~u : (u | 0x80000000u);
}
__device__ __forceinline__ float dec_f32(unsigned e) {
  unsigned u = (e & 0x80000000u) ? (e & 0x7FFFFFFFu) : ~e;
  return __uint_as_float(u);
}

// ---------- kernels ----------

__global__ __launch_bounds__(1024) void vq_init_kernel(double* __restrict__ u123,
                                                       double* __restrict__ loss_part,
                                                       unsigned* __restrict__ maxenc,
                                                       unsigned* __restrict__ minenc) {
  int t = threadIdx.x;
  for (int i = t; i < 3 * KCB; i += 1024) u123[i] = 0.0;
  loss_part[t] = 0.0;
  if (t == 0) {
    *maxenc = 0u;
    *minenc = 0xFFFFFFFFu;
  }
}

__global__ __launch_bounds__(128) void vq_normalize_rows(const float* __restrict__ in,
                                                         float* __restrict__ out) {
  int row = blockIdx.x;
  int t = threadIdx.x;
  float v = in[(size_t)row * DDIM + t];
  float s = v * v;
#pragma unroll
  for (int off = 32; off; off >>= 1) s += __shfl_down(s, off, 64);
  __shared__ float red[2];
  if ((t & 63) == 0) red[t >> 6] = s;
  __syncthreads();
  float norm = sqrtf(red[0] + red[1]);
  out[(size_t)row * DDIM + t] = v / fmaxf(norm, 1e-12f);
}

#define BM 128
#define BN 128
#define BK 32
#define LDK (BK + 4)

__global__ __launch_bounds__(256, 2) void vq_gemm_cos(const float* __restrict__ A,
                                                      const float* __restrict__ B,
                                                      float* __restrict__ Cm,
                                                      unsigned* __restrict__ maxenc,
                                                      unsigned* __restrict__ minenc) {
  __shared__ float As[BM][LDK];
  __shared__ float Bs[BN][LDK];
  int tid = threadIdx.x;
  int tx = tid & 15;   // column group
  int ty = tid >> 4;   // row group
  int n0 = blockIdx.y * BM;
  int c0 = blockIdx.x * BN;
  float acc[8][8] = {};

#pragma unroll 1
  for (int kc = 0; kc < DDIM; kc += BK) {
#pragma unroll
    for (int l = 0; l < 4; ++l) {
      int idx = tid + l * 256;     // 0..1023 float4 groups
      int row = idx >> 3;          // 0..127
      int k4  = (idx & 7) * 4;     // 0..28
      *(float4*)&As[row][k4] = *(const float4*)&A[(size_t)(n0 + row) * DDIM + kc + k4];
      *(float4*)&Bs[row][k4] = *(const float4*)&B[(size_t)(c0 + row) * DDIM + kc + k4];
    }
    __syncthreads();
#pragma unroll 1
    for (int kk = 0; kk < BK; kk += 4) {
      float4 av[8];
#pragma unroll
      for (int i = 0; i < 8; ++i) av[i] = *(const float4*)&As[ty + 16 * i][kk];
#pragma unroll
      for (int j = 0; j < 8; ++j) {
        float4 bv = *(const float4*)&Bs[tx + 16 * j][kk];
#pragma unroll
        for (int i = 0; i < 8; ++i)
          acc[i][j] += av[i].x * bv.x + av[i].y * bv.y + av[i].z * bv.z + av[i].w * bv.w;
      }
    }
    __syncthreads();
  }

  float mx = -3.402823466e38f, mn = 3.402823466e38f;
#pragma unroll
  for (int i = 0; i < 8; ++i) {
#pragma unroll
    for (int j = 0; j < 8; ++j) {
      float v = acc[i][j];
      mx = fmaxf(mx, v);
      mn = fminf(mn, v);
      Cm[(size_t)(n0 + ty + 16 * i) * KCB + (c0 + tx + 16 * j)] = v;
    }
  }
#pragma unroll
  for (int off = 32; off; off >>= 1) {
    mx = fmaxf(mx, __shfl_down(mx, off, 64));
    mn = fminf(mn, __shfl_down(mn, off, 64));
  }
  if ((tid & 63) == 0) {
    atomicMax(maxenc, enc_f32(mx));
    atomicMin(minenc, enc_f32(mn));
  }
}

// scal: [0]=middle, [1]=amplitude, [2]=rc_amp
__global__ void vq_scalarize(const unsigned* __restrict__ maxenc,
                             const unsigned* __restrict__ minenc,
                             float* __restrict__ scal) {
  float cosmax = dec_f32(*maxenc);
  float cosmin = dec_f32(*minenc);
  float mx_d = (1.0f - cosmin) / 0.2f;
  float mn_d = (1.0f - cosmax) / 0.2f;
  float middle = (mx_d + mn_d) / 2.0f;
  float amplitude = fmaxf(mx_d - middle + 1e-5f, 1e-5f);
  scal[0] = middle;
  scal[1] = amplitude;
  scal[2] = 1.0f / amplitude;
}

#define SROWS 32
// If Rvec == null: u_out[k] += sum_n E[n,k]            (first Sinkhorn row pass)
// Else: per row n compute C = 1/(alpha*N*sum_k E*R[k]); u_out[k] += E*C (fused col+row pass)
__global__ __launch_bounds__(256) void vq_sweep(const float* __restrict__ Cm,
                                                const float* __restrict__ scal,
                                                const double* __restrict__ Rvec,
                                                const double* __restrict__ alpha_p,
                                                double* __restrict__ u_out) {
  int t = threadIdx.x;
  int n0 = blockIdx.x * SROWS;
  float middle = scal[0], amp = scal[1], rc_amp = scal[2];
  __shared__ double red[4];
  __shared__ double s_C;
  double Rreg[4];
  double ainv = 0.0;
  if (Rvec) {
#pragma unroll
    for (int j = 0; j < 4; ++j) Rreg[j] = Rvec[t + 256 * j];
    ainv = alpha_p[0] * 32768.0;
  }
  double up[4] = {0.0, 0.0, 0.0, 0.0};
  for (int r = 0; r < SROWS; ++r) {
    size_t base = (size_t)(n0 + r) * KCB + t;
    double e[4];
#pragma unroll
    for (int j = 0; j < 4; ++j)
      e[j] = sweep_E(Cm[base + 256 * j], middle, amp, rc_amp);
    double C = 1.0;
    if (Rvec) {
      double s = e[0] * Rreg[0] + e[1] * Rreg[1] + e[2] * Rreg[2] + e[3] * Rreg[3];
#pragma unroll
      for (int off = 32; off; off >>= 1) s += __shfl_down(s, off, 64);
      if ((t & 63) == 0) red[t >> 6] = s;
      __syncthreads();
      if (t == 0) s_C = 1.0 / (ainv * (red[0] + red[1] + red[2] + red[3]));
      __syncthreads();
      C = s_C;
    }
#pragma unroll
    for (int j = 0; j < 4; ++j) up[j] += e[j] * C;
  }
#pragma unroll
  for (int j = 0; j < 4; ++j) atomic_add_f64(&u_out[t + 256 * j], up[j]);
}

// mode 0: also compute alpha = 1/max(sum u, 1e-5); mode 2: also lnR
__global__ __launch_bounds__(1024) void vq_finalize_u(const double* __restrict__ u,
                                                      double* __restrict__ alpha_p,
                                                      double* __restrict__ R,
                                                      double* __restrict__ lnR,
                                                      int mode) {
  int k = threadIdx.x;
  double uk = u[k];
  __shared__ double red[16];
  __shared__ double s_alpha;
  if (mode == 0) {
    double s = uk;
#pragma unroll
    for (int off = 32; off; off >>= 1) s += __shfl_down(s, off, 64);
    if ((k & 63) == 0) red[k >> 6] = s;
    __syncthreads();
    if (k == 0) {
      double s0 = 0.0;
      for (int w = 0; w < 16; ++w) s0 += red[w];
      double a = 1.0 / fmax(s0, 1e-5);
      s_alpha = a;
      alpha_p[0] = a;
    }
    __syncthreads();
  }
  double alpha = (mode == 0) ? s_alpha : alpha_p[0];
  double r = 1.0 / (alpha * 1024.0 * uk);
  R[k] = r;
  if (mode == 2) lnR[k] = log(r);
}

// per row: argmax_k(-dc/eps + lnR[k]) -> index, gather codebook, CE loss
__global__ __launch_bounds__(256) void vq_final_pass(const float* __restrict__ Cm,
                                                     const float* __restrict__ x,
                                                     const float* __restrict__ cb,
                                                     const double* __restrict__ lnR,
                                                     const float* __restrict__ scal,
                                                     double* __restrict__ loss_part,
                                                     float* __restrict__ out_xq,
                                                     float* __restrict__ out_idx) {
  int n = blockIdx.x;
  int t = threadIdx.x;
  float middle = scal[0], amplitude = scal[1];
  __shared__ double sred[4];
  __shared__ int skred[4];
  __shared__ float sfred[4];
  __shared__ int s_bk;
  __shared__ float s_lbest;

  float lv[4];
  double best = -1.0e308;
  int bestk = 0;
  float lmax = -3.402823466e38f;
#pragma unroll
  for (int j = 0; j < 4; ++j) {
    int k = t + 256 * j;
    float cv = Cm[(size_t)n * KCB + k];
    double score = score_exponent(cv, middle, amplitude) + lnR[k];
    if (score > best) { best = score; bestk = k; }  // ascending k: strict > keeps first max
    float l = cv / 0.2f;
    lv[j] = l;
    lmax = fmaxf(lmax, l);
  }
#pragma unroll
  for (int off = 32; off; off >>= 1) {
    double ob = __shfl_down(best, off, 64);
    int ok = __shfl_down(bestk, off, 64);
    float om = __shfl_down(lmax, off, 64);
    if (ob > best || (ob == best && ok < bestk)) { best = ob; bestk = ok; }
    lmax = fmaxf(lmax, om);
  }
  int lane = t & 63, wid = t >> 6;
  if (lane == 0) { sred[wid] = best; skred[wid] = bestk; sfred[wid] = lmax; }
  __syncthreads();
  if (t == 0) {
    double b = sred[0]; int bk = skred[0]; float m = sfred[0];
    for (int w = 1; w < 4; ++w) {
      if (sred[w] > b || (sred[w] == b && skred[w] < bk)) { b = sred[w]; bk = skred[w]; }
      m = fmaxf(m, sfred[w]);
    }
    s_bk = bk;
    sfred[0] = m;
  }
  __syncthreads();
  int bk = s_bk;
  float lm = sfred[0];
  double se = 0.0;
#pragma unroll
  for (int j = 0; j < 4; ++j) {
    se += (double)expf(lv[j] - lm);
    if (t + 256 * j == bk) s_lbest = lv[j];
  }
#pragma unroll
  for (int off = 32; off; off >>= 1) se += __shfl_down(se, off, 64);
  __syncthreads();  // protect sred reuse; also orders s_lbest write before read
  if (lane == 0) sred[wid] = se;
  __syncthreads();
  if (t == 0) {
    double set = sred[0] + sred[1] + sred[2] + sred[3];
    double loss_n = -((double)s_lbest - (double)lm - log(set));
    atomic_add_f64(&loss_part[n & (KCB - 1)], loss_n);
    out_idx[n] = (float)bk;
  }
  if (t < DDIM) {
    float xf = x[(size_t)n * DDIM + t];
    float cbv = cb[(size_t)bk * DDIM + t];
    out_xq[(size_t)n * DDIM + t] = xf + (cbv - xf);  // STE forward, f32 like ref
  }
}

__global__ __launch_bounds__(1024) void vq_loss_div(const double* __restrict__ lp,
                                                    float* __restrict__ out_loss) {
  int t = threadIdx.x;
  double s = lp[t];
#pragma unroll
  for (int off = 32; off; off >>= 1) s += __shfl_down(s, off, 64);
  __shared__ double red[16];
  if ((t & 63) == 0) red[t >> 6] = s;
  __syncthreads();
  if (t == 0) {
    double tot = 0.0;
    for (int w = 0; w < 16; ++w) tot += red[w];
    out_loss[0] = (float)(tot / 32768.0);
  }
}

// ---------- launch ----------

extern "C" void kernel_launch(void* const* d_in, const int* in_sizes, int n_in,
                              void* d_out, int out_size, void* d_ws, size_t ws_size,
                              hipStream_t stream) {
  const float* x  = (const float*)d_in[0];
  const float* cb = (const float*)d_in[1];
  float* out = (float*)d_out;
  float* out_xq   = out;
  float* out_loss = out + (size_t)NPTS * DDIM;
  float* out_idx  = out + (size_t)NPTS * DDIM + 1;

  // workspace layout (~152 MB)
  char* w = (char*)d_ws;
  float* xn   = (float*)w;                         // N*D
  float* cn   = xn + (size_t)NPTS * DDIM;          // K*D
  float* cosm = cn + (size_t)KCB * DDIM;           // N*K
  double* u1  = (double*)(cosm + (size_t)NPTS * KCB);
  double* u2  = u1 + KCB;
  double* u3  = u2 + KCB;
  double* R   = u3 + KCB;
  double* lnR = R + KCB;
  double* loss_part = lnR + KCB;                   // 1024
  double* alpha_p   = loss_part + KCB;
  unsigned* maxenc = (unsigned*)(alpha_p + 1);
  unsigned* minenc = maxenc + 1;
  float* scal = (float*)(minenc + 1);              // middle, amplitude, rc_amp

  vq_init_kernel<<<1, 1024, 0, stream>>>(u1, loss_part, maxenc, minenc);
  vq_normalize_rows<<<NPTS, 128, 0, stream>>>(x, xn);
  vq_normalize_rows<<<KCB, 128, 0, stream>>>(cb, cn);
  vq_gemm_cos<<<dim3(KCB / BN, NPTS / BM), 256, 0, stream>>>(xn, cn, cosm, maxenc, minenc);
  vq_scalarize<<<1, 1, 0, stream>>>(maxenc, minenc, scal);

  // Sinkhorn: u1 -> R1 ; (v1+u2 fused) -> R2 ; (v2+u3 fused) -> R3, lnR3
  vq_sweep<<<NPTS / SROWS, 256, 0, stream>>>(cosm, scal, nullptr, alpha_p, u1);
  vq_finalize_u<<<1, 1024, 0, stream>>>(u1, alpha_p, R, lnR, 0);
  vq_sweep<<<NPTS / SROWS, 256, 0, stream>>>(cosm, scal, R, alpha_p, u2);
  vq_finalize_u<<<1, 1024, 0, stream>>>(u2, alpha_p, R, lnR, 1);
  vq_sweep<<<NPTS / SROWS, 256, 0, stream>>>(cosm, scal, R, alpha_p, u3);
  vq_finalize_u<<<1, 1024, 0, stream>>>(u3, alpha_p, R, lnR, 2);

  vq_final_pass<<<NPTS, 256, 0, stream>>>(cosm, x, cb, lnR, scal, loss_part, out_xq, out_idx);
  vq_loss_div<<<1, 1024, 0, stream>>>(loss_part, out_loss);
}

// Round 3
// 491.735 us; speedup vs baseline: 3.0994x; 1.1231x over previous
//
#include <hip/hip_runtime.h>
#include <cstddef>

#define NPTS 32768
#define DDIM 128
#define KCB  1024

// ---------- numeric helpers ----------

__device__ __forceinline__ float hw_exp2(float x) {
#if __has_builtin(__builtin_amdgcn_exp2f)
  return __builtin_amdgcn_exp2f(x);
#else
  return exp2f(x);
#endif
}

__device__ __forceinline__ void atomic_add_f64(double* p, double v) {
  __hip_atomic_fetch_add(p, v, __ATOMIC_RELAXED, __HIP_MEMORY_SCOPE_AGENT);
}

// correctly-rounded f32 division via 2-FMA Markstein refinement (rc = RN(1/c))
__device__ __forceinline__ float div_mark(float x, float c, float rc) {
  float q0 = x * rc;
  float r  = fmaf(-c, q0, x);
  return fmaf(r, rc, q0);
}

// E = exp(-dc/eps) with f64 range, rel err ~8e-8 (errors average out in the
// Sinkhorn row/col sums; NOT used for the final argmax score).
__device__ __forceinline__ double sweep_E(float cv, float middle, float amp, float rc_amp) {
  float d  = div_mark(1.0f - cv, 0.2f, 1.0f / 0.2f);
  float dc = div_mark(d - middle, amp, rc_amp);
  double xl2 = (double)dc * (-288.53900817779268);  // 200*log2(e)
  double kd  = rint(xl2);
  float  fr  = (float)(xl2 - kd);
  float  m   = hw_exp2(fr);
  long long bits = ((long long)(1023 + (int)kd)) << 52;
  return (double)m * __longlong_as_double(bits);
}

// bit-exact path (matches jnp f32 ops) for the final argmax score exponent
__device__ __forceinline__ double score_exponent(float cv, float middle, float amplitude) {
  float d  = (1.0f - cv) / 0.2f;
  float dc = (d - middle) / amplitude;
  return (double)dc * (-(1.0 / 0.005));
}

// order-preserving f32 <-> u32 encode for atomic min/max
__device__ __forceinline__ unsigned enc_f32(float f) {
  unsigned u = __float_as_uint(f);
  return (u & 0x80000000u) ? ~u : (u | 0x80000000u);
}
__device__ __forceinline__ float dec_f32(unsigned e) {
  unsigned u = (e & 0x80000000u) ? (e & 0x7FFFFFFFu) : ~e;
  return __uint_as_float(u);
}

// ---------- kernels ----------

__global__ __launch_bounds__(1024) void vq_init_kernel(double* __restrict__ u123,
                                                       double* __restrict__ loss_part,
                                                       unsigned* __restrict__ maxenc,
                                                       unsigned* __restrict__ minenc) {
  int t = threadIdx.x;
  for (int i = t; i < 3 * KCB; i += 1024) u123[i] = 0.0;
  loss_part[t] = 0.0;
  if (t == 0) {
    *maxenc = 0u;
    *minenc = 0xFFFFFFFFu;
  }
}

__global__ __launch_bounds__(128) void vq_normalize_rows(const float* __restrict__ in,
                                                         float* __restrict__ out) {
  int row = blockIdx.x;
  int t = threadIdx.x;
  float v = in[(size_t)row * DDIM + t];
  float s = v * v;
#pragma unroll
  for (int off = 32; off; off >>= 1) s += __shfl_down(s, off, 64);
  __shared__ float red[2];
  if ((t & 63) == 0) red[t >> 6] = s;
  __syncthreads();
  float norm = sqrtf(red[0] + red[1]);
  out[(size_t)row * DDIM + t] = v / fmaxf(norm, 1e-12f);
}

// normalize codebook row and store TRANSPOSED: outT[k][col] (for SGPR-B GEMM)
__global__ __launch_bounds__(128) void vq_normalize_cb_t(const float* __restrict__ in,
                                                         float* __restrict__ outT) {
  int row = blockIdx.x;
  int t = threadIdx.x;
  float v = in[(size_t)row * DDIM + t];
  float s = v * v;
#pragma unroll
  for (int off = 32; off; off >>= 1) s += __shfl_down(s, off, 64);
  __shared__ float red[2];
  if ((t & 63) == 0) red[t >> 6] = s;
  __syncthreads();
  float norm = sqrtf(red[0] + red[1]);
  outT[(size_t)t * KCB + row] = v / fmaxf(norm, 1e-12f);
}

// ---- GEMM: lane = one C-row, block = 256 rows x 64 cols, B from SGPRs ----
#define GR 256
#define GC 64
#define GK 32

__global__ __launch_bounds__(256, 4) void vq_gemm_cos(const float* __restrict__ A,
                                                      const float* __restrict__ Bt,  // [DDIM][KCB]
                                                      float* __restrict__ Cm,
                                                      unsigned* __restrict__ maxenc,
                                                      unsigned* __restrict__ minenc) {
  __shared__ float As[GR][GK + 4];  // stride 36 floats: b128-aligned, mild conflicts OK (rare reads)
  int tid = threadIdx.x;
  int n0 = blockIdx.y * GR;
  int c0 = blockIdx.x * GC;
  float acc[GC] = {};

#pragma unroll 1
  for (int kc = 0; kc < DDIM; kc += GK) {
    // stage A tile: 256 rows x 32 k = 2048 float4 loads, 8 per thread, coalesced
#pragma unroll
    for (int l = 0; l < 8; ++l) {
      int idx = tid + l * 256;
      int row = idx >> 3;
      int k4  = (idx & 7) * 4;
      *(float4*)&As[row][k4] = *(const float4*)&A[(size_t)(n0 + row) * DDIM + kc + k4];
    }
    __syncthreads();
#pragma unroll 1
    for (int k0 = 0; k0 < GK; k0 += 4) {
      float4 a4 = *(const float4*)&As[tid][k0];
      const float* bbase = Bt + (size_t)(kc + k0) * KCB + c0;
#pragma unroll
      for (int kk = 0; kk < 4; ++kk) {
        float av = (kk == 0) ? a4.x : (kk == 1) ? a4.y : (kk == 2) ? a4.z : a4.w;
        const float* brow = bbase + (size_t)kk * KCB;  // wave-uniform -> s_load
#pragma unroll
        for (int cc = 0; cc < GC; ++cc)
          acc[cc] = fmaf(av, brow[cc], acc[cc]);
      }
    }
    __syncthreads();
  }

  float mx = -3.402823466e38f, mn = 3.402823466e38f;
#pragma unroll
  for (int cc = 0; cc < GC; ++cc) {
    mx = fmaxf(mx, acc[cc]);
    mn = fminf(mn, acc[cc]);
  }
  float* crow = Cm + (size_t)(n0 + tid) * KCB + c0;
#pragma unroll
  for (int cc = 0; cc < GC; cc += 4) {
    float4 v4 = make_float4(acc[cc], acc[cc + 1], acc[cc + 2], acc[cc + 3]);
    *(float4*)&crow[cc] = v4;
  }
#pragma unroll
  for (int off = 32; off; off >>= 1) {
    mx = fmaxf(mx, __shfl_down(mx, off, 64));
    mn = fminf(mn, __shfl_down(mn, off, 64));
  }
  if ((tid & 63) == 0) {
    atomicMax(maxenc, enc_f32(mx));
    atomicMin(minenc, enc_f32(mn));
  }
}

// scal: [0]=middle, [1]=amplitude, [2]=rc_amp
__global__ void vq_scalarize(const unsigned* __restrict__ maxenc,
                             const unsigned* __restrict__ minenc,
                             float* __restrict__ scal) {
  float cosmax = dec_f32(*maxenc);
  float cosmin = dec_f32(*minenc);
  float mx_d = (1.0f - cosmin) / 0.2f;
  float mn_d = (1.0f - cosmax) / 0.2f;
  float middle = (mx_d + mn_d) / 2.0f;
  float amplitude = fmaxf(mx_d - middle + 1e-5f, 1e-5f);
  scal[0] = middle;
  scal[1] = amplitude;
  scal[2] = 1.0f / amplitude;
}

// ---- Sinkhorn sweep: wave-per-row, zero per-row barriers ----
// Each block: 4 waves x 16 rows = 64 rows. Lane covers k = c*256 + lane*4 + e.
// Rvec==null: u_out[k] += sum_n E[n,k]
// else: per row C = 1/(alpha*N*sum_k E*R[k]); u_out[k] += E*C
#define SROWS 64

__global__ __launch_bounds__(256) void vq_sweep(const float* __restrict__ Cm,
                                                const float* __restrict__ scal,
                                                const double* __restrict__ Rvec,
                                                const double* __restrict__ alpha_p,
                                                double* __restrict__ u_out) {
  int t = threadIdx.x;
  int lane = t & 63, wv = t >> 6;
  int n0 = blockIdx.x * SROWS + wv * 16;
  float middle = scal[0], amp = scal[1], rc = scal[2];
  bool hasR = (Rvec != nullptr);
  double Rreg[16];
  double ainv = 0.0;
  if (hasR) {
#pragma unroll
    for (int c = 0; c < 4; ++c)
#pragma unroll
      for (int e = 0; e < 4; ++e) Rreg[c * 4 + e] = Rvec[c * 256 + lane * 4 + e];
    ainv = alpha_p[0] * 32768.0;
  }
  double up[16] = {};
#pragma unroll 1
  for (int r = 0; r < 16; ++r) {
    const float4* row = (const float4*)(Cm + (size_t)(n0 + r) * KCB);
    float4 cv[4];
#pragma unroll
    for (int c = 0; c < 4; ++c) cv[c] = row[c * 64 + lane];
    double e[16];
#pragma unroll
    for (int c = 0; c < 4; ++c) {
      e[c * 4 + 0] = sweep_E(cv[c].x, middle, amp, rc);
      e[c * 4 + 1] = sweep_E(cv[c].y, middle, amp, rc);
      e[c * 4 + 2] = sweep_E(cv[c].z, middle, amp, rc);
      e[c * 4 + 3] = sweep_E(cv[c].w, middle, amp, rc);
    }
    if (hasR) {
      double s = 0.0;
#pragma unroll
      for (int i = 0; i < 16; ++i) s += e[i] * Rreg[i];
#pragma unroll
      for (int off = 1; off < 64; off <<= 1) s += __shfl_xor(s, off, 64);
      double C = 1.0 / (ainv * s);
#pragma unroll
      for (int i = 0; i < 16; ++i) up[i] += e[i] * C;
    } else {
#pragma unroll
      for (int i = 0; i < 16; ++i) up[i] += e[i];
    }
  }
  // combine the block's 4 waves in LDS, then one atomic per k per block
  __shared__ double su[4][KCB];  // 32 KB
#pragma unroll
  for (int c = 0; c < 4; ++c)
#pragma unroll
    for (int e = 0; e < 4; ++e) su[wv][c * 256 + lane * 4 + e] = up[c * 4 + e];
  __syncthreads();
  for (int k = t; k < KCB; k += 256) {
    double v = su[0][k] + su[1][k] + su[2][k] + su[3][k];
    atomic_add_f64(&u_out[k], v);
  }
}

// mode 0: also compute alpha = 1/max(sum u, 1e-5); mode 2: also lnR
__global__ __launch_bounds__(1024) void vq_finalize_u(const double* __restrict__ u,
                                                      double* __restrict__ alpha_p,
                                                      double* __restrict__ R,
                                                      double* __restrict__ lnR,
                                                      int mode) {
  int k = threadIdx.x;
  double uk = u[k];
  __shared__ double red[16];
  __shared__ double s_alpha;
  if (mode == 0) {
    double s = uk;
#pragma unroll
    for (int off = 32; off; off >>= 1) s += __shfl_down(s, off, 64);
    if ((k & 63) == 0) red[k >> 6] = s;
    __syncthreads();
    if (k == 0) {
      double s0 = 0.0;
      for (int w = 0; w < 16; ++w) s0 += red[w];
      double a = 1.0 / fmax(s0, 1e-5);
      s_alpha = a;
      alpha_p[0] = a;
    }
    __syncthreads();
  }
  double alpha = (mode == 0) ? s_alpha : alpha_p[0];
  double r = 1.0 / (alpha * 1024.0 * uk);
  R[k] = r;
  if (mode == 2) lnR[k] = log(r);
}

// ---- final pass: wave-per-row; argmax + CE loss + gather, zero barriers ----
#define FRPW 8  // rows per wave

__global__ __launch_bounds__(256) void vq_final_pass(const float* __restrict__ Cm,
                                                     const float* __restrict__ x,
                                                     const float* __restrict__ cb,
                                                     const double* __restrict__ lnR,
                                                     const float* __restrict__ scal,
                                                     double* __restrict__ loss_part,
                                                     float* __restrict__ out_xq,
                                                     float* __restrict__ out_idx) {
  int t = threadIdx.x;
  int lane = t & 63, wv = t >> 6;
  int n0 = blockIdx.x * (4 * FRPW) + wv * FRPW;
  float middle = scal[0], amplitude = scal[1];
  double lnRreg[16];
#pragma unroll
  for (int c = 0; c < 4; ++c)
#pragma unroll
    for (int e = 0; e < 4; ++e) lnRreg[c * 4 + e] = lnR[c * 256 + lane * 4 + e];

  double loss_loc = 0.0;
#pragma unroll 1
  for (int r = 0; r < FRPW; ++r) {
    int n = n0 + r;
    const float4* row = (const float4*)(Cm + (size_t)n * KCB);
    float4 cv[4];
#pragma unroll
    for (int c = 0; c < 4; ++c) cv[c] = row[c * 64 + lane];
    float lv[16];
    double best = -1.0e308;
    int bestk = 0;
    float lmax = -3.402823466e38f;
#pragma unroll
    for (int c = 0; c < 4; ++c) {
#pragma unroll
      for (int e = 0; e < 4; ++e) {
        float cvv = (e == 0) ? cv[c].x : (e == 1) ? cv[c].y : (e == 2) ? cv[c].z : cv[c].w;
        int k = c * 256 + lane * 4 + e;  // ascending within lane
        double score = score_exponent(cvv, middle, amplitude) + lnRreg[c * 4 + e];
        if (score > best) { best = score; bestk = k; }
        float l = cvv / 0.2f;
        lv[c * 4 + e] = l;
        lmax = fmaxf(lmax, l);
      }
    }
    // butterfly argmax (tie -> smaller k) + max reduce; all lanes converge
#pragma unroll
    for (int off = 1; off < 64; off <<= 1) {
      double ob = __shfl_xor(best, off, 64);
      int ok = __shfl_xor(bestk, off, 64);
      float om = __shfl_xor(lmax, off, 64);
      if (ob > best || (ob == best && ok < bestk)) { best = ob; bestk = ok; }
      lmax = fmaxf(lmax, om);
    }
    // sum exp + extract l[bestk]
    double se = 0.0;
    float lb = 0.0f;
#pragma unroll
    for (int c = 0; c < 4; ++c) {
#pragma unroll
      for (int e = 0; e < 4; ++e) {
        int k = c * 256 + lane * 4 + e;
        se += (double)expf(lv[c * 4 + e] - lmax);
        if (k == bestk) lb = lv[c * 4 + e];
      }
    }
#pragma unroll
    for (int off = 1; off < 64; off <<= 1) {
      se += __shfl_xor(se, off, 64);
      lb += __shfl_xor(lb, off, 64);  // exactly one lane nonzero
    }
    loss_loc += -((double)lb - (double)lmax - log(se));
    if (lane == 0) out_idx[n] = (float)bestk;
    // STE forward in f32 exactly like ref: x + (x_q - x)
    float2 xv = *(const float2*)&x[(size_t)n * DDIM + lane * 2];
    float2 cbv = *(const float2*)&cb[(size_t)bestk * DDIM + lane * 2];
    float2 o;
    o.x = xv.x + (cbv.x - xv.x);
    o.y = xv.y + (cbv.y - xv.y);
    *(float2*)&out_xq[(size_t)n * DDIM + lane * 2] = o;
  }
  if (lane == 0) atomic_add_f64(&loss_part[(blockIdx.x * 4 + wv) & (KCB - 1)], loss_loc);
}

__global__ __launch_bounds__(1024) void vq_loss_div(const double* __restrict__ lp,
                                                    float* __restrict__ out_loss) {
  int t = threadIdx.x;
  double s = lp[t];
#pragma unroll
  for (int off = 32; off; off >>= 1) s += __shfl_down(s, off, 64);
  __shared__ double red[16];
  if ((t & 63) == 0) red[t >> 6] = s;
  __syncthreads();
  if (t == 0) {
    double tot = 0.0;
    for (int w = 0; w < 16; ++w) tot += red[w];
    out_loss[0] = (float)(tot / 32768.0);
  }
}

// ---------- launch ----------

extern "C" void kernel_launch(void* const* d_in, const int* in_sizes, int n_in,
                              void* d_out, int out_size, void* d_ws, size_t ws_size,
                              hipStream_t stream) {
  const float* x  = (const float*)d_in[0];
  const float* cb = (const float*)d_in[1];
  float* out = (float*)d_out;
  float* out_xq   = out;
  float* out_loss = out + (size_t)NPTS * DDIM;
  float* out_idx  = out + (size_t)NPTS * DDIM + 1;

  // workspace layout (~152 MB)
  char* w = (char*)d_ws;
  float* xn   = (float*)w;                         // N*D
  float* bt   = xn + (size_t)NPTS * DDIM;          // D*K (transposed normalized codebook)
  float* cosm = bt + (size_t)DDIM * KCB;           // N*K
  double* u1  = (double*)(cosm + (size_t)NPTS * KCB);
  double* u2  = u1 + KCB;
  double* u3  = u2 + KCB;
  double* R   = u3 + KCB;
  double* lnR = R + KCB;
  double* loss_part = lnR + KCB;                   // 1024
  double* alpha_p   = loss_part + KCB;
  unsigned* maxenc = (unsigned*)(alpha_p + 1);
  unsigned* minenc = maxenc + 1;
  float* scal = (float*)(minenc + 1);              // middle, amplitude, rc_amp

  vq_init_kernel<<<1, 1024, 0, stream>>>(u1, loss_part, maxenc, minenc);
  vq_normalize_rows<<<NPTS, 128, 0, stream>>>(x, xn);
  vq_normalize_cb_t<<<KCB, 128, 0, stream>>>(cb, bt);
  vq_gemm_cos<<<dim3(KCB / GC, NPTS / GR), 256, 0, stream>>>(xn, bt, cosm, maxenc, minenc);
  vq_scalarize<<<1, 1, 0, stream>>>(maxenc, minenc, scal);

  // Sinkhorn: u1 -> R1 ; (v1+u2 fused) -> R2 ; (v2+u3 fused) -> R3, lnR3
  vq_sweep<<<NPTS / SROWS, 256, 0, stream>>>(cosm, scal, nullptr, alpha_p, u1);
  vq_finalize_u<<<1, 1024, 0, stream>>>(u1, alpha_p, R, lnR, 0);
  vq_sweep<<<NPTS / SROWS, 256, 0, stream>>>(cosm, scal, R, alpha_p, u2);
  vq_finalize_u<<<1, 1024, 0, stream>>>(u2, alpha_p, R, lnR, 1);
  vq_sweep<<<NPTS / SROWS, 256, 0, stream>>>(cosm, scal, R, alpha_p, u3);
  vq_finalize_u<<<1, 1024, 0, stream>>>(u3, alpha_p, R, lnR, 2);

  vq_final_pass<<<NPTS / (4 * FRPW), 256, 0, stream>>>(cosm, x, cb, lnR, scal, loss_part,
                                                       out_xq, out_idx);
  vq_loss_div<<<1, 1024, 0, stream>>>(loss_part, out_loss);
}